// Round 3
// baseline (75.313 us; speedup 1.0000x reference)
//
#include <hip/hip_runtime.h>
#include <math.h>

// YOLO loss, 3 scales: G in {13,26,52}, B=32, A=3, 85 ch (5+80), IMG=416.
// Inputs (setup_inputs dict order): fm0, yt0, fm1, yt1, fm2, yt2, anchors(9x2)
// Output: 5 floats: total, xy, wh, conf, prob

constexpr int   NCLS  = 80;
constexpr int   KMAX  = 32;
constexpr float IMGF  = 416.0f;

// cells per scale: 32 * 3 * G*G
constexpr int C0 = 32 * 3 * 169;    // 16224
constexpr int C1 = 32 * 3 * 676;    // 64896
constexpr int C2 = 32 * 3 * 2704;   // 259584
constexpr int TOTAL_CELLS = C0 + C1 + C2; // 340704

constexpr int NBLK_POS  = 96;                  // one per (scale, batch)
constexpr int NBLK_CONF = 96 + 288 + 1056;     // 1440
constexpr int NBLK_MAIN = NBLK_POS + NBLK_CONF;// 1536

// ws layout (fully rewritten every call):
//   [0,16)    float acc[4]        : xy, wh, conf, prob raw sums (f32 atomics)
//   [16,20)   unsigned done       : ticket counter
//   [32,416)  int cnt[96]
//   [448,...) float4 tgt[96][32]  : x,y,w,h
//   [...,...) int tgtn[96][32]
constexpr size_t OFF_ACC  = 0;
constexpr size_t OFF_DONE = 16;
constexpr size_t OFF_CNT  = 32;
constexpr size_t OFF_TGT  = 448;
constexpr size_t OFF_TGTN = OFF_TGT + (size_t)96 * KMAX * 16;   // 49600

__global__ __launch_bounds__(128) void k_init(int* wsi) {
    int t = threadIdx.x;
    if (t < 112) wsi[t] = 0;   // covers acc, done, cnt ([0,448) bytes)
}

__global__ __launch_bounds__(256) void k_collect(
        const float* __restrict__ yt0, const float* __restrict__ yt1,
        const float* __restrict__ yt2,
        int* __restrict__ cnt, float* __restrict__ tgt, int* __restrict__ tgtn) {
    int t = blockIdx.x * 256 + threadIdx.x;
    if (t >= TOTAL_CELLS) return;
    int s, local, G;
    const float* yt;
    if (t < C0)           { s = 0; local = t;           G = 13; yt = yt0; }
    else if (t < C0 + C1) { s = 1; local = t - C0;      G = 26; yt = yt1; }
    else                  { s = 2; local = t - C0 - C1; G = 52; yt = yt2; }
    int GG = G * G;
    int b  = local / (3 * GG);
    int n  = local - b * 3 * GG;          // b-relative flattened cell index
    int yidx = local * 85;
    float obj = yt[yidx + 4];
    if (obj > 0.5f) {
        int pos = atomicAdd(&cnt[s * 32 + b], 1);
        if (pos < KMAX) {
            float4 box = make_float4(yt[yidx], yt[yidx + 1], yt[yidx + 2], yt[yidx + 3]);
            reinterpret_cast<float4*>(tgt)[(s * 32 + b) * KMAX + pos] = box;
            tgtn[(s * 32 + b) * KMAX + pos] = n;
        }
    }
}

__device__ inline float sigmoidf_(float x) { return 1.0f / (1.0f + expf(-x)); }
__device__ inline float bcef_(float l, float t) {
    return fmaxf(l, 0.0f) - l * t + log1pf(expf(-fabsf(l)));
}

// Fused: blocks [0,96) = positive-cell losses (xy/wh/class), one block per (s,b);
//        blocks [96,1536) = conf loss over all cells.
// Each block atomicAdds its f32 partial into acc[4]; last block (ticket) emits out[5].
__global__ __launch_bounds__(256) void k_main(
        const float* __restrict__ fm0, const float* __restrict__ fm1,
        const float* __restrict__ fm2,
        const float* __restrict__ yt0, const float* __restrict__ yt1,
        const float* __restrict__ yt2,
        const float* __restrict__ anch,
        const int* __restrict__ cnt, const float* __restrict__ tgt,
        const int* __restrict__ tgtn,
        float* __restrict__ acc, unsigned* __restrict__ done,
        float* __restrict__ out) {
    __shared__ float s_minx[KMAX], s_maxx[KMAX], s_miny[KMAX], s_maxy[KMAX], s_area[KMAX];
    __shared__ int   s_tn[KMAX];
    __shared__ int   s_cn;
    __shared__ float4 s_w4[4];
    __shared__ float  s_w1[4];
    __shared__ unsigned s_tick;

    int bid = blockIdx.x;
    int tid = threadIdx.x;
    int wid = tid >> 6, lane = tid & 63;

    if (bid < NBLK_POS) {
        // ---- positive-cell losses ----
        int sb = bid, s = sb >> 5, b = sb & 31;
        const float *fm, *yt;
        int G, anchoff;
        if (s == 0)      { fm = fm0; yt = yt0; G = 13; anchoff = 6; }
        else if (s == 1) { fm = fm1; yt = yt1; G = 26; anchoff = 3; }
        else             { fm = fm2; yt = yt2; G = 52; anchoff = 0; }
        int GG = G * G;
        float stridef = IMGF / (float)G;
        int cn = min(cnt[sb], KMAX);
        float accx = 0.f, accw = 0.f, accp = 0.f;   // lane0-only accumulation
        for (int slot = wid; slot < cn; slot += 4) {
            float4 tb = reinterpret_cast<const float4*>(tgt)[sb * KMAX + slot];
            int n  = tgtn[sb * KMAX + slot];
            int a  = n % 3;
            int sp = n / 3;
            int jj = sp % G, ii = sp / G;
            int ybase = (b * 3 * GG + n) * 85;
            int fbase = (b * 255 + a * 85) * GG + sp;
            float ps = 0.0f;
            for (int c = lane; c < NCLS; c += 64) {
                float pl  = fm[fbase + (5 + c) * GG];
                float tl  = yt[ybase + 5 + c];
                float lab = 0.99f * tl + 1.25e-4f;   // (1-delta)*t + delta/NC
                ps += bcef_(pl, lab);
            }
            for (int off = 32; off; off >>= 1) ps += __shfl_down(ps, off);
            if (lane == 0) {
                float p0 = fm[fbase];
                float p1 = fm[fbase + GG];
                float p2 = fm[fbase + 2 * GG];
                float p3 = fm[fbase + 3 * GG];
                float bcx = (sigmoidf_(p0) + (float)jj) * stridef;
                float bcy = (sigmoidf_(p1) + (float)ii) * stridef;
                float predx = bcx / stridef - (float)jj;
                float predy = bcy / stridef - (float)ii;
                float truex = tb.x / stridef - (float)jj;
                float truey = tb.y / stridef - (float)ii;
                float dx = truex - predx, dy = truey - predy;
                float bscale = 2.0f - (tb.z / IMGF) * (tb.w / IMGF);
                float aw = anch[(anchoff + a) * 2], ah = anch[(anchoff + a) * 2 + 1];
                float pw = expf(p2) * (aw / stridef) * stridef;
                float ph = expf(p3) * (ah / stridef) * stridef;
                float ptw = pw / aw, pth = ph / ah;
                float ttw = tb.z / aw, tth = tb.w / ah;
                ttw = (ttw == 0.0f) ? 1.0f : ttw;
                tth = (tth == 0.0f) ? 1.0f : tth;
                ptw = (ptw == 0.0f) ? 1.0f : ptw;
                pth = (pth == 0.0f) ? 1.0f : pth;
                ttw = logf(fminf(fmaxf(ttw, 1e-9f), 1e9f));
                tth = logf(fminf(fmaxf(tth, 1e-9f), 1e9f));
                ptw = logf(fminf(fmaxf(ptw, 1e-9f), 1e9f));
                pth = logf(fminf(fmaxf(pth, 1e-9f), 1e9f));
                float dw = ttw - ptw, dh = tth - pth;
                accx += (dx * dx + dy * dy) * bscale;
                accw += (dw * dw + dh * dh) * bscale;
                accp += ps;
            }
        }
        if (lane == 0) s_w4[wid] = make_float4(accx, accw, accp, 0.f);
        __syncthreads();
        if (tid == 0) {
            float4 r0 = s_w4[0], r1 = s_w4[1], r2 = s_w4[2], r3 = s_w4[3];
            float X = r0.x + r1.x + r2.x + r3.x;
            float W = r0.y + r1.y + r2.y + r3.y;
            float P = r0.z + r1.z + r2.z + r3.z;
            if (X != 0.f) atomicAdd(&acc[0], X);
            if (W != 0.f) atomicAdd(&acc[1], W);
            if (P != 0.f) atomicAdd(&acc[3], P);
        }
    } else {
        // ---- conf loss over all cells ----
        int cb = bid - NBLK_POS;
        const float *fm;
        int G, chunks, s, anchoff;
        if (cb < 96)       { fm = fm0; G = 13; chunks = 1;  s = 0; anchoff = 6; }
        else if (cb < 384) { cb -= 96;  fm = fm1; G = 26; chunks = 3;  s = 1; anchoff = 3; }
        else               { cb -= 384; fm = fm2; G = 52; chunks = 11; s = 2; anchoff = 0; }
        int chunk = cb % chunks;
        int ba    = cb / chunks;     // b*3 + a
        int b = ba / 3, a = ba % 3;
        int GG = G * G;
        float stridef = IMGF / (float)G;
        int sb = s * 32 + b;

        if (tid == 0) s_cn = min(cnt[sb], KMAX);
        if (tid < KMAX) {
            float4 tb = reinterpret_cast<const float4*>(tgt)[sb * KMAX + tid];
            s_minx[tid] = tb.x - tb.z * 0.5f;
            s_maxx[tid] = tb.x + tb.z * 0.5f;
            s_miny[tid] = tb.y - tb.w * 0.5f;
            s_maxy[tid] = tb.y + tb.w * 0.5f;
            s_area[tid] = tb.z * tb.w;
            s_tn[tid]   = tgtn[sb * KMAX + tid];
        }
        __syncthreads();

        int sp = chunk * 256 + tid;
        float local = 0.0f;
        if (sp < GG) {
            int jj = sp % G, ii = sp / G;
            int n = sp * 3 + a;
            int fbase = (b * 255 + a * 85) * GG + sp;
            float p0 = fm[fbase];
            float p1 = fm[fbase + GG];
            float p2 = fm[fbase + 2 * GG];
            float p3 = fm[fbase + 3 * GG];
            float p4 = fm[fbase + 4 * GG];
            float aw = anch[(anchoff + a) * 2], ah = anch[(anchoff + a) * 2 + 1];
            float cx = (sigmoidf_(p0) + (float)jj) * stridef;
            float cy = (sigmoidf_(p1) + (float)ii) * stridef;
            float pw = expf(p2) * (aw / stridef) * stridef;
            float ph = expf(p3) * (ah / stridef) * stridef;
            float pminx = cx - pw * 0.5f, pmaxx = cx + pw * 0.5f;
            float pminy = cy - ph * 0.5f, pmaxy = cy + ph * 0.5f;
            float parea = pw * ph;
            int cn = s_cn;
            float best = 0.0f;
            float m = 0.0f;
            for (int k = 0; k < cn; ++k) {
                if (s_tn[k] == n) m = 1.0f;
                float iw = fminf(pmaxx, s_maxx[k]) - fmaxf(pminx, s_minx[k]);
                float ih = fminf(pmaxy, s_maxy[k]) - fmaxf(pminy, s_miny[k]);
                iw = fmaxf(iw, 0.0f);
                ih = fmaxf(ih, 0.0f);
                float inter = iw * ih;
                float iou = inter / ((parea + s_area[k] - inter) + 1e-10f);
                best = fmaxf(best, iou);
            }
            float ign = (cn > 0 && best < 0.5f) ? 1.0f : 0.0f;
            float bce = bcef_(p4, m);
            float d = fabsf(m - sigmoidf_(p4));
            local = (m * bce + 0.5f * (1.0f - m) * ign * bce) * (d * d);
        }
        for (int off = 32; off; off >>= 1) local += __shfl_down(local, off);
        if (lane == 0) s_w1[wid] = local;
        __syncthreads();
        if (tid == 0) {
            float Cc = s_w1[0] + s_w1[1] + s_w1[2] + s_w1[3];
            atomicAdd(&acc[2], Cc);
        }
    }

    // ---- ticket: last block finalizes ----
    if (tid == 0) {
        __threadfence();                 // acc atomics globally performed first
        s_tick = atomicAdd(done, 1u);
    }
    __syncthreads();
    if (s_tick == (unsigned)(NBLK_MAIN - 1) && tid == 0) {
        float X  = atomicAdd(&acc[0], 0.0f);   // coherent reads
        float W  = atomicAdd(&acc[1], 0.0f);
        float Cc = atomicAdd(&acc[2], 0.0f);
        float P  = atomicAdd(&acc[3], 0.0f);
        double xy = 5.0 * (double)X / 32.0;
        double wh = 5.0 * (double)W / 32.0;
        double cf = (double)Cc / 32.0;
        double pb = (double)P / 32.0;
        out[0] = (float)(xy + wh + cf + pb);
        out[1] = (float)xy;
        out[2] = (float)wh;
        out[3] = (float)cf;
        out[4] = (float)pb;
    }
}

extern "C" void kernel_launch(void* const* d_in, const int* in_sizes, int n_in,
                              void* d_out, int out_size, void* d_ws, size_t ws_size,
                              hipStream_t stream) {
    const float* fm0  = (const float*)d_in[0];
    const float* yt0  = (const float*)d_in[1];
    const float* fm1  = (const float*)d_in[2];
    const float* yt1  = (const float*)d_in[3];
    const float* fm2  = (const float*)d_in[4];
    const float* yt2  = (const float*)d_in[5];
    const float* anch = (const float*)d_in[6];
    float* out = (float*)d_out;

    char* ws = (char*)d_ws;
    float*    acc  = (float*)(ws + OFF_ACC);
    unsigned* done = (unsigned*)(ws + OFF_DONE);
    int*      cnt  = (int*)(ws + OFF_CNT);
    float*    tgt  = (float*)(ws + OFF_TGT);
    int*      tgtn = (int*)(ws + OFF_TGTN);

    k_init<<<1, 128, 0, stream>>>((int*)ws);
    k_collect<<<(TOTAL_CELLS + 255) / 256, 256, 0, stream>>>(
        yt0, yt1, yt2, cnt, tgt, tgtn);
    k_main<<<NBLK_MAIN, 256, 0, stream>>>(
        fm0, fm1, fm2, yt0, yt1, yt2, anch, cnt, tgt, tgtn, acc, done, out);
}

// Round 4
// 41.551 us; speedup vs baseline: 1.8126x; 1.8126x over previous
//
#include <hip/hip_runtime.h>
#include <math.h>

// YOLO loss, 3 scales: G in {13,26,52}, B=32, A=3, 85 ch (5+80), IMG=416.
// Inputs (setup_inputs dict order): fm0, yt0, fm1, yt1, fm2, yt2, anchors(9x2)
// Output: 5 floats: total, xy, wh, conf, prob
//
// NOTE (hard-won): hipcc lowers atomicAdd(float*)/atomicAdd(double*) on global
// memory to CAS loops (no -munsafe-fp-atomics here). Contended fp atomics cost
// ~40ns per success serialized -> NEVER use them. Int atomics are native.

constexpr int   NCLS  = 80;
constexpr int   KMAX  = 32;
constexpr float IMGF  = 416.0f;

// cells per scale: 32 * 3 * G*G
constexpr int C0 = 32 * 3 * 169;    // 16224
constexpr int C1 = 32 * 3 * 676;    // 64896
constexpr int C2 = 32 * 3 * 2704;   // 259584
constexpr int TOTAL_CELLS = C0 + C1 + C2; // 340704

constexpr int NBLK_POS  = 96;                  // one per (scale, batch)
constexpr int NBLK_CONF = 96 + 288 + 1056;     // 1440
constexpr int NBLK_MAIN = NBLK_POS + NBLK_CONF;// 1536

// ws layout (every slot rewritten every call; no cross-call state):
//   [OFF_PART) float4 part[1536]   : per-block partials (xy, wh, prob, conf)
//   [OFF_CNT)  int    cnt[96]
//   [OFF_TGT)  float4 tgt[96][32]  : x,y,w,h
//   [OFF_TGTN) int    tgtn[96][32]
constexpr size_t OFF_PART = 0;
constexpr size_t OFF_CNT  = (size_t)NBLK_MAIN * 16;                 // 24576
constexpr size_t OFF_TGT  = OFF_CNT + 96 * sizeof(int);             // 24960
constexpr size_t OFF_TGTN = OFF_TGT + (size_t)96 * KMAX * 16;       // 74112

__global__ __launch_bounds__(128) void k_init(int* cnt) {
    int t = threadIdx.x;
    if (t < 96) cnt[t] = 0;
}

__global__ __launch_bounds__(256) void k_collect(
        const float* __restrict__ yt0, const float* __restrict__ yt1,
        const float* __restrict__ yt2,
        int* __restrict__ cnt, float* __restrict__ tgt, int* __restrict__ tgtn) {
    int t = blockIdx.x * 256 + threadIdx.x;
    if (t >= TOTAL_CELLS) return;
    int s, local, G;
    const float* yt;
    if (t < C0)           { s = 0; local = t;           G = 13; yt = yt0; }
    else if (t < C0 + C1) { s = 1; local = t - C0;      G = 26; yt = yt1; }
    else                  { s = 2; local = t - C0 - C1; G = 52; yt = yt2; }
    int GG = G * G;
    int b  = local / (3 * GG);
    int n  = local - b * 3 * GG;          // b-relative flattened cell index
    int yidx = local * 85;
    float obj = yt[yidx + 4];
    if (obj > 0.5f) {
        int pos = atomicAdd(&cnt[s * 32 + b], 1);   // int atomic: native, cheap
        if (pos < KMAX) {
            float4 box = make_float4(yt[yidx], yt[yidx + 1], yt[yidx + 2], yt[yidx + 3]);
            reinterpret_cast<float4*>(tgt)[(s * 32 + b) * KMAX + pos] = box;
            tgtn[(s * 32 + b) * KMAX + pos] = n;
        }
    }
}

__device__ inline float sigmoidf_(float x) { return 1.0f / (1.0f + expf(-x)); }
__device__ inline float bcef_(float l, float t) {
    return fmaxf(l, 0.0f) - l * t + log1pf(expf(-fabsf(l)));
}

// Fused: blocks [0,96)      = positive-cell losses (xy/wh/class), one per (s,b);
//        blocks [96,1536)   = conf loss over all cells.
// Each block writes its partial (xy, wh, prob, conf) to part[bid]. No fp atomics.
__global__ __launch_bounds__(256) void k_main(
        const float* __restrict__ fm0, const float* __restrict__ fm1,
        const float* __restrict__ fm2,
        const float* __restrict__ yt0, const float* __restrict__ yt1,
        const float* __restrict__ yt2,
        const float* __restrict__ anch,
        const int* __restrict__ cnt, const float* __restrict__ tgt,
        const int* __restrict__ tgtn, float4* __restrict__ part) {
    __shared__ float s_minx[KMAX], s_maxx[KMAX], s_miny[KMAX], s_maxy[KMAX], s_area[KMAX];
    __shared__ int   s_tn[KMAX];
    __shared__ int   s_cn;
    __shared__ float4 s_w4[4];
    __shared__ float  s_w1[4];

    int bid = blockIdx.x;
    int tid = threadIdx.x;
    int wid = tid >> 6, lane = tid & 63;

    if (bid < NBLK_POS) {
        // ---- positive-cell losses ----
        int sb = bid, s = sb >> 5, b = sb & 31;
        const float *fm, *yt;
        int G, anchoff;
        if (s == 0)      { fm = fm0; yt = yt0; G = 13; anchoff = 6; }
        else if (s == 1) { fm = fm1; yt = yt1; G = 26; anchoff = 3; }
        else             { fm = fm2; yt = yt2; G = 52; anchoff = 0; }
        int GG = G * G;
        float stridef = IMGF / (float)G;
        int cn = min(cnt[sb], KMAX);
        float accx = 0.f, accw = 0.f, accp = 0.f;   // lane0-only accumulation
        for (int slot = wid; slot < cn; slot += 4) {
            float4 tb = reinterpret_cast<const float4*>(tgt)[sb * KMAX + slot];
            int n  = tgtn[sb * KMAX + slot];
            int a  = n % 3;
            int sp = n / 3;
            int jj = sp % G, ii = sp / G;
            int ybase = (b * 3 * GG + n) * 85;
            int fbase = (b * 255 + a * 85) * GG + sp;
            float ps = 0.0f;
            for (int c = lane; c < NCLS; c += 64) {
                float pl  = fm[fbase + (5 + c) * GG];
                float tl  = yt[ybase + 5 + c];
                float lab = 0.99f * tl + 1.25e-4f;   // (1-delta)*t + delta/NC
                ps += bcef_(pl, lab);
            }
            for (int off = 32; off; off >>= 1) ps += __shfl_down(ps, off);
            if (lane == 0) {
                float p0 = fm[fbase];
                float p1 = fm[fbase + GG];
                float p2 = fm[fbase + 2 * GG];
                float p3 = fm[fbase + 3 * GG];
                float bcx = (sigmoidf_(p0) + (float)jj) * stridef;
                float bcy = (sigmoidf_(p1) + (float)ii) * stridef;
                float predx = bcx / stridef - (float)jj;
                float predy = bcy / stridef - (float)ii;
                float truex = tb.x / stridef - (float)jj;
                float truey = tb.y / stridef - (float)ii;
                float dx = truex - predx, dy = truey - predy;
                float bscale = 2.0f - (tb.z / IMGF) * (tb.w / IMGF);
                float aw = anch[(anchoff + a) * 2], ah = anch[(anchoff + a) * 2 + 1];
                float pw = expf(p2) * (aw / stridef) * stridef;
                float ph = expf(p3) * (ah / stridef) * stridef;
                float ptw = pw / aw, pth = ph / ah;
                float ttw = tb.z / aw, tth = tb.w / ah;
                ttw = (ttw == 0.0f) ? 1.0f : ttw;
                tth = (tth == 0.0f) ? 1.0f : tth;
                ptw = (ptw == 0.0f) ? 1.0f : ptw;
                pth = (pth == 0.0f) ? 1.0f : pth;
                ttw = logf(fminf(fmaxf(ttw, 1e-9f), 1e9f));
                tth = logf(fminf(fmaxf(tth, 1e-9f), 1e9f));
                ptw = logf(fminf(fmaxf(ptw, 1e-9f), 1e9f));
                pth = logf(fminf(fmaxf(pth, 1e-9f), 1e9f));
                float dw = ttw - ptw, dh = tth - pth;
                accx += (dx * dx + dy * dy) * bscale;
                accw += (dw * dw + dh * dh) * bscale;
                accp += ps;
            }
        }
        if (lane == 0) s_w4[wid] = make_float4(accx, accw, accp, 0.f);
        __syncthreads();
        if (tid == 0) {
            float4 r0 = s_w4[0], r1 = s_w4[1], r2 = s_w4[2], r3 = s_w4[3];
            part[bid] = make_float4(r0.x + r1.x + r2.x + r3.x,
                                    r0.y + r1.y + r2.y + r3.y,
                                    r0.z + r1.z + r2.z + r3.z,
                                    0.0f);
        }
    } else {
        // ---- conf loss over all cells ----
        int cb = bid - NBLK_POS;
        const float *fm;
        int G, chunks, s, anchoff;
        if (cb < 96)       { fm = fm0; G = 13; chunks = 1;  s = 0; anchoff = 6; }
        else if (cb < 384) { cb -= 96;  fm = fm1; G = 26; chunks = 3;  s = 1; anchoff = 3; }
        else               { cb -= 384; fm = fm2; G = 52; chunks = 11; s = 2; anchoff = 0; }
        int chunk = cb % chunks;
        int ba    = cb / chunks;     // b*3 + a
        int b = ba / 3, a = ba % 3;
        int GG = G * G;
        float stridef = IMGF / (float)G;
        int sb = s * 32 + b;

        if (tid == 0) s_cn = min(cnt[sb], KMAX);
        if (tid < KMAX) {
            float4 tb = reinterpret_cast<const float4*>(tgt)[sb * KMAX + tid];
            s_minx[tid] = tb.x - tb.z * 0.5f;
            s_maxx[tid] = tb.x + tb.z * 0.5f;
            s_miny[tid] = tb.y - tb.w * 0.5f;
            s_maxy[tid] = tb.y + tb.w * 0.5f;
            s_area[tid] = tb.z * tb.w;
            s_tn[tid]   = tgtn[sb * KMAX + tid];
        }
        __syncthreads();

        int sp = chunk * 256 + tid;
        float local = 0.0f;
        if (sp < GG) {
            int jj = sp % G, ii = sp / G;
            int n = sp * 3 + a;
            int fbase = (b * 255 + a * 85) * GG + sp;
            float p0 = fm[fbase];
            float p1 = fm[fbase + GG];
            float p2 = fm[fbase + 2 * GG];
            float p3 = fm[fbase + 3 * GG];
            float p4 = fm[fbase + 4 * GG];
            float aw = anch[(anchoff + a) * 2], ah = anch[(anchoff + a) * 2 + 1];
            float cx = (sigmoidf_(p0) + (float)jj) * stridef;
            float cy = (sigmoidf_(p1) + (float)ii) * stridef;
            float pw = expf(p2) * (aw / stridef) * stridef;
            float ph = expf(p3) * (ah / stridef) * stridef;
            float pminx = cx - pw * 0.5f, pmaxx = cx + pw * 0.5f;
            float pminy = cy - ph * 0.5f, pmaxy = cy + ph * 0.5f;
            float parea = pw * ph;
            int cn = s_cn;
            float best = 0.0f;
            float m = 0.0f;
            for (int k = 0; k < cn; ++k) {
                if (s_tn[k] == n) m = 1.0f;
                float iw = fminf(pmaxx, s_maxx[k]) - fmaxf(pminx, s_minx[k]);
                float ih = fminf(pmaxy, s_maxy[k]) - fmaxf(pminy, s_miny[k]);
                iw = fmaxf(iw, 0.0f);
                ih = fmaxf(ih, 0.0f);
                float inter = iw * ih;
                float iou = inter / ((parea + s_area[k] - inter) + 1e-10f);
                best = fmaxf(best, iou);
            }
            float ign = (cn > 0 && best < 0.5f) ? 1.0f : 0.0f;
            float bce = bcef_(p4, m);
            float d = fabsf(m - sigmoidf_(p4));
            local = (m * bce + 0.5f * (1.0f - m) * ign * bce) * (d * d);
        }
        for (int off = 32; off; off >>= 1) local += __shfl_down(local, off);
        if (lane == 0) s_w1[wid] = local;
        __syncthreads();
        if (tid == 0)
            part[bid] = make_float4(0.f, 0.f, 0.f, s_w1[0] + s_w1[1] + s_w1[2] + s_w1[3]);
    }
}

// Sum the 1536 per-block partials (double accumulation) and emit the 5 outputs.
__global__ __launch_bounds__(512) void k_reduce(
        const float4* __restrict__ part, float* __restrict__ out) {
    int t = threadIdx.x;
    double x = 0.0, w = 0.0, p = 0.0, c = 0.0;
    for (int i = t; i < NBLK_MAIN; i += 512) {
        float4 v = part[i];
        x += (double)v.x; w += (double)v.y; p += (double)v.z; c += (double)v.w;
    }
    for (int off = 32; off; off >>= 1) {
        x += __shfl_down(x, off);
        w += __shfl_down(w, off);
        p += __shfl_down(p, off);
        c += __shfl_down(c, off);
    }
    __shared__ double sx[8], sw[8], sp[8], sc[8];
    int wid = t >> 6, lane = t & 63;
    if (lane == 0) { sx[wid] = x; sw[wid] = w; sp[wid] = p; sc[wid] = c; }
    __syncthreads();
    if (t == 0) {
        double X = 0, W = 0, P = 0, C = 0;
        for (int i = 0; i < 8; ++i) { X += sx[i]; W += sw[i]; P += sp[i]; C += sc[i]; }
        double xy = 5.0 * X / 32.0;
        double wh = 5.0 * W / 32.0;
        double cf = C / 32.0;
        double pb = P / 32.0;
        out[0] = (float)(xy + wh + cf + pb);
        out[1] = (float)xy;
        out[2] = (float)wh;
        out[3] = (float)cf;
        out[4] = (float)pb;
    }
}

extern "C" void kernel_launch(void* const* d_in, const int* in_sizes, int n_in,
                              void* d_out, int out_size, void* d_ws, size_t ws_size,
                              hipStream_t stream) {
    const float* fm0  = (const float*)d_in[0];
    const float* yt0  = (const float*)d_in[1];
    const float* fm1  = (const float*)d_in[2];
    const float* yt1  = (const float*)d_in[3];
    const float* fm2  = (const float*)d_in[4];
    const float* yt2  = (const float*)d_in[5];
    const float* anch = (const float*)d_in[6];
    float* out = (float*)d_out;

    char* ws = (char*)d_ws;
    float4* part = (float4*)(ws + OFF_PART);
    int*    cnt  = (int*)(ws + OFF_CNT);
    float*  tgt  = (float*)(ws + OFF_TGT);
    int*    tgtn = (int*)(ws + OFF_TGTN);

    k_init<<<1, 128, 0, stream>>>(cnt);
    k_collect<<<(TOTAL_CELLS + 255) / 256, 256, 0, stream>>>(
        yt0, yt1, yt2, cnt, tgt, tgtn);
    k_main<<<NBLK_MAIN, 256, 0, stream>>>(
        fm0, fm1, fm2, yt0, yt1, yt2, anch, cnt, tgt, tgtn, part);
    k_reduce<<<1, 512, 0, stream>>>(part, out);
}